// Round 1
// baseline (1520.931 us; speedup 1.0000x reference)
//
#include <hip/hip_runtime.h>
#include <math.h>

// Pairwise average over x rows (D=128). One thread per output float4.
// Output row i (32 float4) = avg of input rows 2i and 2i+1.
__global__ void x_avg_kernel(const float4* __restrict__ x,
                             float4* __restrict__ xo,
                             long total /* = S*32 */) {
    long i = (long)blockIdx.x * blockDim.x + threadIdx.x;
    if (i >= total) return;
    long seg = i >> 5;   // output row (32 float4 per 128-float row)
    long j   = i & 31;   // float4 index within row
    float4 a = x[seg * 64 + j];        // row 2*seg
    float4 b = x[seg * 64 + 32 + j];   // row 2*seg+1
    float4 o;
    o.x = (a.x + b.x) * 0.5f;
    o.y = (a.y + b.y) * 0.5f;
    o.z = (a.z + b.z) * 0.5f;
    o.w = (a.w + b.w) * 0.5f;
    xo[i] = o;
}

// pos mean, seq max(>>1), ori mean+normalize, batch max. One thread per segment.
__global__ void misc_kernel(const float* __restrict__ pos,
                            const int*   __restrict__ seq,
                            const float* __restrict__ ori,
                            const int*   __restrict__ batch,
                            float* __restrict__ pos_out,
                            float* __restrict__ seq_out,
                            float* __restrict__ ori_out,
                            float* __restrict__ batch_out,
                            int S) {
    int s = blockIdx.x * blockDim.x + threadIdx.x;
    if (s >= S) return;
    long p0 = (long)(2 * s) * 3;

    // pos: mean of two consecutive 3-vectors
    float px = (pos[p0 + 0] + pos[p0 + 3]) * 0.5f;
    float py = (pos[p0 + 1] + pos[p0 + 4]) * 0.5f;
    float pz = (pos[p0 + 2] + pos[p0 + 5]) * 0.5f;
    long o3 = (long)s * 3;
    pos_out[o3 + 0] = px;
    pos_out[o3 + 1] = py;
    pos_out[o3 + 2] = pz;

    // ori: mean then L2-normalize (clamped at 1e-12 like the reference)
    float ox = (ori[p0 + 0] + ori[p0 + 3]) * 0.5f;
    float oy = (ori[p0 + 1] + ori[p0 + 4]) * 0.5f;
    float oz = (ori[p0 + 2] + ori[p0 + 5]) * 0.5f;
    float nrm = sqrtf(ox * ox + oy * oy + oz * oz);
    float inv = 1.0f / fmaxf(nrm, 1e-12f);
    ori_out[o3 + 0] = ox * inv;
    ori_out[o3 + 1] = oy * inv;
    ori_out[o3 + 2] = oz * inv;

    // seq: max of floor(seq/2) over the pair (values non-negative: >>1 == //2)
    int s0 = seq[2 * s]     >> 1;
    int s1 = seq[2 * s + 1] >> 1;
    seq_out[s] = (float)(s0 > s1 ? s0 : s1);

    // batch: max over the pair
    int b0 = batch[2 * s];
    int b1 = batch[2 * s + 1];
    batch_out[s] = (float)(b0 > b1 ? b0 : b1);
}

extern "C" void kernel_launch(void* const* d_in, const int* in_sizes, int n_in,
                              void* d_out, int out_size, void* d_ws, size_t ws_size,
                              hipStream_t stream) {
    const float* x     = (const float*)d_in[0];
    const float* pos   = (const float*)d_in[1];
    const int*   seq   = (const int*)d_in[2];
    const float* ori   = (const float*)d_in[3];
    const int*   batch = (const int*)d_in[4];

    const int N = in_sizes[2];  // seq has N elements
    const int S = N / 2;        // number of segments (pairs)

    float* out       = (float*)d_out;
    float* x_out     = out;                        // S*128
    float* pos_out   = out + (size_t)S * 128;      // S*3
    float* seq_out   = out + (size_t)S * 131;      // S*1
    float* ori_out   = out + (size_t)S * 132;      // S*3
    float* batch_out = out + (size_t)S * 135;      // S*1

    const long total = (long)S * 32;  // output float4 count for x
    const int block = 256;
    const long grid_x = (total + block - 1) / block;
    x_avg_kernel<<<dim3((unsigned)grid_x), dim3(block), 0, stream>>>(
        (const float4*)x, (float4*)x_out, total);

    const int grid_m = (S + block - 1) / block;
    misc_kernel<<<dim3(grid_m), dim3(block), 0, stream>>>(
        pos, seq, ori, batch, pos_out, seq_out, ori_out, batch_out, S);
}